// Round 4
// baseline (108.248 us; speedup 1.0000x reference)
//
#include <hip/hip_runtime.h>
#include <stdint.h>

#define N_ROWS 65536
#define K_CODES 1024
#define DIM 256

typedef unsigned int uint;
typedef unsigned short ushort;

// d_ws layout:
//   [0, 4K)       loss accumulator (first 4B)
//   [4K, 8K)      enorm[1024] fp32
//   [8K, +512K)   Ebf: bf16 codebook, 512B per code
#define WS_LOSS_OFF  0
#define WS_ENORM_OFF 4096
#define WS_EBF_OFF   8192

typedef __attribute__((ext_vector_type(8))) short bf16x8;
typedef __attribute__((ext_vector_type(4))) float f32x4;

__device__ __forceinline__ ushort f2bf(float f) {
    uint u = __float_as_uint(f);
    return (ushort)((u + 0x7FFFu + ((u >> 16) & 1u)) >> 16);   // RNE
}
__device__ __forceinline__ float bf2f(ushort h) {
    return __uint_as_float(((uint)h) << 16);
}
__device__ __forceinline__ void gload_lds16(const void* g, void* l) {
    __builtin_amdgcn_global_load_lds(
        (const __attribute__((address_space(1))) void*)g,
        (__attribute__((address_space(3))) void*)l, 16, 0, 0);
}

// ---- prep: E -> bf16 codebook + exact fp32 squared norms ------------------
__global__ __launch_bounds__(256) void vq_prep(const float* __restrict__ E,
                                               ushort* __restrict__ Ebf,
                                               float* __restrict__ enorm) {
    int id = blockIdx.x * 256 + threadIdx.x;      // 65536 = 1024 codes * 64 f4
    int code = id >> 6, c4 = id & 63;
    float4 v = *reinterpret_cast<const float4*>(E + (size_t)code * DIM + c4 * 4);
    uint2 hi;
    hi.x = (uint)f2bf(v.x) | ((uint)f2bf(v.y) << 16);
    hi.y = (uint)f2bf(v.z) | ((uint)f2bf(v.w) << 16);
    *reinterpret_cast<uint2*>((char*)Ebf + (size_t)code * 512 + c4 * 8) = hi;

    float s = v.x * v.x + v.y * v.y + v.z * v.z + v.w * v.w;
    #pragma unroll
    for (int m = 32; m >= 1; m >>= 1) s += __shfl_down(s, m, 64);
    if (c4 == 0) enorm[code] = s;
}

// ---- fused main: barrier-free wave-private MFMA + argmin + out + loss -----
// Block: 128 rows. 4 waves: wave w -> rows (w>>1)*64..+64, codes (w&1)*512..+512.
// Per wave: 32 tiles of 16 codes (8KB), 3-deep rotating wave-private LDS slices,
// counted vmcnt (T4). A frags resident in regs (m=4). No barriers in main loop.
__global__ __launch_bounds__(256, 1) void vq_main(const float* __restrict__ X,
                                                  const ushort* __restrict__ Ebf,
                                                  const float* __restrict__ enorm,
                                                  const float* __restrict__ E,
                                                  float* __restrict__ out,
                                                  float* __restrict__ lossAcc) {
    // arenas: [0,32K)=A rows 0-63 / arena0, [32K,64K)=A rows 64-127 / arena1,
    // [64K,96K)=arena2. Arena slice per wave: 8KB.
    __shared__ __align__(16) unsigned char sm[98304];
    __shared__ float enormLds[1024];
    __shared__ float redScore[2][128];
    __shared__ int   redCode[2][128];
    __shared__ float normLds[128];
    __shared__ int   bcLds[128];
    __shared__ float lossSh;

    const int tid = threadIdx.x;
    const int lane = tid & 63;
    const int w = tid >> 6;
    const int cl = lane & 15;
    const int kq = lane >> 4;
    const int r = w >> 1;          // row-half
    const int cHalf = w & 1;       // code-half
    const int row0 = blockIdx.x * 128;

    auto stageB = [&](int tile, int aidx) {
        unsigned char* dst = sm + aidx * 32768 + w * 8192;
        const unsigned char* src = (const unsigned char*)Ebf
            + ((size_t)(cHalf * 512 + tile * 16)) * 512;
        #pragma unroll
        for (int j = 0; j < 8; ++j) {
            int o = j * 1024 + lane * 16;
            int rr = o >> 9;
            int cb = (o & 511) ^ ((rr & 7) << 4);   // pre-swizzled source (rule 21)
            gload_lds16(src + rr * 512 + cb, dst + j * 1024);
        }
    };

    stageB(0, 2);                       // arena2: no conflict with A region

    *reinterpret_cast<float4*>(&enormLds[tid * 4]) =
        *reinterpret_cast<const float4*>(&enorm[tid * 4]);
    if (tid == 0) lossSh = 0.f;

    // A: coalesced global f4 -> bf16 -> LDS rows (XOR-swizzled, T2)
    #pragma unroll
    for (int i = 0; i < 32; ++i) {
        int g = i * 256 + tid;          // 8192 f4 = 128 rows x 64
        int rr = g >> 6, c4 = g & 63;
        float4 v = *reinterpret_cast<const float4*>(
            X + (size_t)(row0 + rr) * DIM + c4 * 4);
        uint2 p;
        p.x = (uint)f2bf(v.x) | ((uint)f2bf(v.y) << 16);
        p.y = (uint)f2bf(v.z) | ((uint)f2bf(v.w) << 16);
        *reinterpret_cast<uint2*>(sm + rr * 512 + ((c4 * 8) ^ ((rr & 7) << 4))) = p;
    }
    __syncthreads();                    // b1: A staged (also drains stage(0))

    // A fragments -> regs, + bf16-accurate row norms
    bf16x8 aF[4][8];
    float nrm[4];
    #pragma unroll
    for (int m = 0; m < 4; ++m) {
        int row_l = r * 64 + m * 16 + cl;
        const unsigned char* ar = sm + row_l * 512;
        int key = (row_l & 7) << 4;
        float s = 0.f;
        #pragma unroll
        for (int ks = 0; ks < 8; ++ks) {
            bf16x8 f = *reinterpret_cast<const bf16x8*>(ar + ((ks * 64 + kq * 16) ^ key));
            aF[m][ks] = f;
            #pragma unroll
            for (int j = 0; j < 8; ++j) {
                float e = bf2f((ushort)f[j]);
                s = fmaf(e, e, s);
            }
        }
        s += __shfl_xor(s, 16, 64);
        s += __shfl_xor(s, 32, 64);
        nrm[m] = s;
    }
    __syncthreads();                    // b2: A region reusable as arenas 0/1

    if (kq == 0) {
        #pragma unroll
        for (int m = 0; m < 4; ++m)
            normLds[r * 64 + m * 16 + cl] = nrm[m];
    }

    stageB(1, 0);

    float best[4][4];
    int bcode[4][4];
    #pragma unroll
    for (int m = 0; m < 4; ++m)
        #pragma unroll
        for (int rr = 0; rr < 4; ++rr) { best[m][rr] = 3.4e38f; bcode[m][rr] = 0; }

    for (int t = 0; t < 32; ++t) {
        if (t < 30) stageB(t + 2, (t + 1) % 3);
        // wave-local counted wait: tile t resident, t+1/t+2 still in flight (T4)
        if (t < 30)       { asm volatile("s_waitcnt vmcnt(16)" ::: "memory"); }
        else if (t == 30) { asm volatile("s_waitcnt vmcnt(8)"  ::: "memory"); }
        else              { asm volatile("s_waitcnt vmcnt(0)"  ::: "memory"); }

        const unsigned char* bb = sm + ((t + 2) % 3) * 32768 + w * 8192;
        float en = enormLds[cHalf * 512 + t * 16 + cl];

        f32x4 acc[4];
        #pragma unroll
        for (int m = 0; m < 4; ++m) {
            f32x4 z = {0.f, 0.f, 0.f, 0.f};
            acc[m] = z;
        }

        __builtin_amdgcn_s_setprio(1);
        #pragma unroll
        for (int ks = 0; ks < 8; ++ks) {
            bf16x8 bf = *reinterpret_cast<const bf16x8*>(
                bb + cl * 512 + ((ks * 64 + kq * 16) ^ ((cl & 7) << 4)));
            #pragma unroll
            for (int m = 0; m < 4; ++m)
                acc[m] = __builtin_amdgcn_mfma_f32_16x16x32_bf16(
                    aF[m][ks], bf, acc[m], 0, 0, 0);
        }
        __builtin_amdgcn_s_setprio(0);

        int codeBase = cHalf * 512 + t * 16 + cl;
        #pragma unroll
        for (int m = 0; m < 4; ++m)
            #pragma unroll
            for (int rr = 0; rr < 4; ++rr) {
                float s = fmaf(-2.f, acc[m][rr], en);
                if (s < best[m][rr]) { best[m][rr] = s; bcode[m][rr] = codeBase; }
            }
    }

    // cross-cl reduce; C-row = m*16 + kq*4 + rr (m89 layout)
    #pragma unroll
    for (int m = 0; m < 4; ++m)
        #pragma unroll
        for (int rr = 0; rr < 4; ++rr) {
            float b = best[m][rr];
            int cc = bcode[m][rr];
            #pragma unroll
            for (int mask = 1; mask < 16; mask <<= 1) {
                float ob = __shfl_xor(b, mask, 64);
                int oc = __shfl_xor(cc, mask, 64);
                if (ob < b || (ob == b && oc < cc)) { b = ob; cc = oc; }
            }
            if (cl == 0) {
                int row_l = r * 64 + m * 16 + kq * 4 + rr;
                redScore[cHalf][row_l] = b;
                redCode[cHalf][row_l] = cc;
            }
        }
    __syncthreads();                    // b3

    // combine code-halves, accumulate loss
    if (tid < 128) {
        float s0 = redScore[0][tid], s1 = redScore[1][tid];
        int c0 = redCode[0][tid], c1 = redCode[1][tid];
        int code = (s1 < s0) ? c1 : c0;          // tie -> c0 (smaller index)
        float sc = (s1 < s0) ? s1 : s0;
        bcLds[tid] = code;
        float lsum = normLds[tid] + sc;          // ||x||^2 + ||e||^2 - 2 x.e
        #pragma unroll
        for (int mask = 32; mask >= 1; mask >>= 1)
            lsum += __shfl_xor(lsum, mask, 64);
        if (lane == 0) atomicAdd(&lossSh, lsum);
    }
    __syncthreads();                    // b4: bcLds + lossSh ready

    // out[row] = E[bc[row]]  (== x + (q - x) to ~3e-7)
    #pragma unroll
    for (int i = 0; i < 32; ++i) {
        int g = i * 256 + tid;
        int rr = g >> 6, c4 = g & 63;
        int code = bcLds[rr];
        float4 q = *reinterpret_cast<const float4*>(E + (size_t)code * DIM + c4 * 4);
        *reinterpret_cast<float4*>(out + (size_t)(row0 + rr) * DIM + c4 * 4) = q;
    }
    if (tid == 0) atomicAdd(lossAcc, lossSh);
}

__global__ void vq_finalize(const float* __restrict__ lossAcc,
                            float* __restrict__ out) {
    out[(size_t)N_ROWS * DIM] = 1.25f * lossAcc[0] / (float)((size_t)N_ROWS * DIM);
}

extern "C" void kernel_launch(void* const* d_in, const int* in_sizes, int n_in,
                              void* d_out, int out_size, void* d_ws, size_t ws_size,
                              hipStream_t stream) {
    const float* X = (const float*)d_in[0];
    const float* E = (const float*)d_in[1];
    float* out = (float*)d_out;

    char* ws = (char*)d_ws;
    float* lossAcc = (float*)(ws + WS_LOSS_OFF);
    float* enorm = (float*)(ws + WS_ENORM_OFF);
    ushort* Ebf = (ushort*)(ws + WS_EBF_OFF);

    hipMemsetAsync(lossAcc, 0, 4, stream);
    vq_prep<<<256, 256, 0, stream>>>(E, Ebf, enorm);
    vq_main<<<N_ROWS / 128, 256, 0, stream>>>(X, Ebf, enorm, E, out, lossAcc);
    vq_finalize<<<1, 1, 0, stream>>>(lossAcc, out);
}

// Round 5
// 105.503 us; speedup vs baseline: 1.0260x; 1.0260x over previous
//
#include <hip/hip_runtime.h>
#include <stdint.h>

#define N_ROWS 65536
#define K_CODES 1024
#define DIM 256

typedef unsigned int uint;
typedef unsigned short ushort;

// d_ws layout:
//   [0, 4K)       loss accumulator (first 4B)
//   [4K, 8K)      enorm[1024] fp32
//   [8K, +512K)   Ebf: bf16 codebook, 512B per code
#define WS_LOSS_OFF  0
#define WS_ENORM_OFF 4096
#define WS_EBF_OFF   8192

typedef __attribute__((ext_vector_type(8))) short bf16x8;
typedef __attribute__((ext_vector_type(4))) float f32x4;

__device__ __forceinline__ ushort f2bf(float f) {
    uint u = __float_as_uint(f);
    return (ushort)((u + 0x7FFFu + ((u >> 16) & 1u)) >> 16);   // RNE
}
__device__ __forceinline__ void gload_lds16(const void* g, void* l) {
    __builtin_amdgcn_global_load_lds(
        (const __attribute__((address_space(1))) void*)g,
        (__attribute__((address_space(3))) void*)l, 16, 0, 0);
}

// ---- prep: E -> bf16 codebook + exact fp32 squared norms ------------------
__global__ __launch_bounds__(256) void vq_prep(const float* __restrict__ E,
                                               ushort* __restrict__ Ebf,
                                               float* __restrict__ enorm) {
    int id = blockIdx.x * 256 + threadIdx.x;      // 65536 = 1024 codes * 64 f4
    int code = id >> 6, c4 = id & 63;
    float4 v = *reinterpret_cast<const float4*>(E + (size_t)code * DIM + c4 * 4);
    uint2 hi;
    hi.x = (uint)f2bf(v.x) | ((uint)f2bf(v.y) << 16);
    hi.y = (uint)f2bf(v.z) | ((uint)f2bf(v.w) << 16);
    *reinterpret_cast<uint2*>((char*)Ebf + (size_t)code * 512 + c4 * 8) = hi;

    float s = v.x * v.x + v.y * v.y + v.z * v.z + v.w * v.w;
    #pragma unroll
    for (int m = 32; m >= 1; m >>= 1) s += __shfl_down(s, m, 64);
    if (c4 == 0) enorm[code] = s;
}

// ---- fused main ------------------------------------------------------------
// Block: 128 threads = 2 waves; each wave owns 64 rows (m=4, A in regs),
// both waves share 32-code B tiles (16KB) staged cooperatively via
// global_load_lds into a 3-deep rotation; counted vmcnt + raw s_barrier
// (no vm drains in the loop). Grid 512 -> 2 independent blocks/CU.
__global__ __launch_bounds__(128, 2) void vq_main(const float* __restrict__ X,
                                                  const ushort* __restrict__ Ebf,
                                                  const float* __restrict__ enorm,
                                                  const float* __restrict__ E,
                                                  float* __restrict__ out,
                                                  float* __restrict__ lossAcc) {
    __shared__ __align__(16) unsigned char bsm[49152];   // 3 x 16KB B tiles
    __shared__ float enormLds[1024];
    __shared__ float normLds[128];
    __shared__ int   bcLds[128];
    __shared__ float lossSh;

    const int tid = threadIdx.x;
    const int lane = tid & 63;
    const int w = tid >> 6;          // wave 0/1
    const int cl = lane & 15;
    const int kq = lane >> 4;
    const int row0 = blockIdx.x * 128;

    auto stageB = [&](int tile, int buf) {
        unsigned char* dst = bsm + buf * 16384 + w * 8192;
        const unsigned char* src = (const unsigned char*)Ebf + (size_t)(tile * 32) * 512;
        #pragma unroll
        for (int j = 0; j < 8; ++j) {
            int o = w * 8192 + j * 1024 + lane * 16;
            int rr = o >> 9;                         // code row in tile
            int cb = (o & 511) ^ ((rr & 7) << 4);    // pre-swizzled source (rule 21)
            gload_lds16(src + rr * 512 + cb, dst + j * 1024);
        }
    };

    stageB(0, 0);
    stageB(1, 1);

    // enorm -> LDS (1024 f32, 2 float4 per thread)
    #pragma unroll
    for (int i = 0; i < 2; ++i) {
        int j = i * 128 + tid;
        reinterpret_cast<float4*>(enormLds)[j] =
            reinterpret_cast<const float4*>(enorm)[j];
    }
    if (tid == 0) lossSh = 0.f;

    // A: global -> reg, bf16 convert in flight; exact fp32 row norms
    bf16x8 aF[4][8];
    #pragma unroll
    for (int m = 0; m < 4; ++m) {
        const float* rp = X + (size_t)(row0 + w * 64 + m * 16 + cl) * DIM;
        float s = 0.f;
        #pragma unroll
        for (int ks = 0; ks < 8; ++ks) {
            float4 v0 = *reinterpret_cast<const float4*>(rp + ks * 32 + kq * 8);
            float4 v1 = *reinterpret_cast<const float4*>(rp + ks * 32 + kq * 8 + 4);
            float e[8] = {v0.x, v0.y, v0.z, v0.w, v1.x, v1.y, v1.z, v1.w};
            bf16x8 f;
            #pragma unroll
            for (int j = 0; j < 8; ++j) {
                f[j] = (short)f2bf(e[j]);
                s = fmaf(e[j], e[j], s);
            }
            aF[m][ks] = f;
        }
        s += __shfl_xor(s, 16, 64);
        s += __shfl_xor(s, 32, 64);
        if (kq == 0) normLds[w * 64 + m * 16 + cl] = s;
    }
    __syncthreads();   // publish enormLds/normLds (also drains stage(0),(1) - ok once)

    float best[4][4];
    int bcode[4][4];
    #pragma unroll
    for (int m = 0; m < 4; ++m)
        #pragma unroll
        for (int rr = 0; rr < 4; ++rr) { best[m][rr] = 3.4e38f; bcode[m][rr] = 0; }

    for (int t = 0; t < 32; ++t) {
        // entry invariant: all waves done reading tile t-1 (end barrier of t-1)
        if (t < 30) stageB(t + 2, (t + 2) % 3);
        // counted wait: my share of stage(t) landed; t+1,t+2 stay in flight (T4)
        if (t < 30)       { asm volatile("s_waitcnt vmcnt(16)" ::: "memory"); }
        else if (t == 30) { asm volatile("s_waitcnt vmcnt(8)"  ::: "memory"); }
        else              { asm volatile("s_waitcnt vmcnt(0)"  ::: "memory"); }
        __builtin_amdgcn_s_barrier();            // everyone's stage(t) visible
        __builtin_amdgcn_sched_barrier(0);

        const unsigned char* bb = bsm + (t % 3) * 16384;
        float en[2];
        en[0] = enormLds[t * 32 + cl];
        en[1] = enormLds[t * 32 + 16 + cl];

        f32x4 acc[4][2];
        #pragma unroll
        for (int m = 0; m < 4; ++m)
            #pragma unroll
            for (int n = 0; n < 2; ++n) {
                f32x4 z = {0.f, 0.f, 0.f, 0.f};
                acc[m][n] = z;
            }

        __builtin_amdgcn_s_setprio(1);
        #pragma unroll
        for (int ks = 0; ks < 8; ++ks) {
            bf16x8 bf0 = *reinterpret_cast<const bf16x8*>(
                bb + (size_t)cl * 512 + ((ks * 64 + kq * 16) ^ ((cl & 7) << 4)));
            bf16x8 bf1 = *reinterpret_cast<const bf16x8*>(
                bb + (size_t)(16 + cl) * 512 + ((ks * 64 + kq * 16) ^ ((cl & 7) << 4)));
            #pragma unroll
            for (int m = 0; m < 4; ++m) {
                acc[m][0] = __builtin_amdgcn_mfma_f32_16x16x32_bf16(
                    aF[m][ks], bf0, acc[m][0], 0, 0, 0);
                acc[m][1] = __builtin_amdgcn_mfma_f32_16x16x32_bf16(
                    aF[m][ks], bf1, acc[m][1], 0, 0, 0);
            }
        }
        __builtin_amdgcn_s_setprio(0);

        // fold scores (codes ascend -> strict < keeps first occurrence)
        #pragma unroll
        for (int n = 0; n < 2; ++n) {
            int codeN = t * 32 + n * 16 + cl;
            #pragma unroll
            for (int m = 0; m < 4; ++m)
                #pragma unroll
                for (int rr = 0; rr < 4; ++rr) {
                    float sc = fmaf(-2.f, acc[m][n][rr], en[n]);
                    if (sc < best[m][rr]) { best[m][rr] = sc; bcode[m][rr] = codeN; }
                }
        }

        asm volatile("s_waitcnt lgkmcnt(0)" ::: "memory");  // my ds_reads of t landed
        __builtin_amdgcn_s_barrier();            // all waves done with buf t%3
        __builtin_amdgcn_sched_barrier(0);
    }

    // epilogue: cross-cl argmin reduce; C-row = m*16 + kq*4 + rr (m89 layout)
    float lsum = 0.f;
    #pragma unroll
    for (int m = 0; m < 4; ++m)
        #pragma unroll
        for (int rr = 0; rr < 4; ++rr) {
            float b = best[m][rr];
            int cc = bcode[m][rr];
            #pragma unroll
            for (int mask = 1; mask < 16; mask <<= 1) {
                float ob = __shfl_xor(b, mask, 64);
                int oc = __shfl_xor(cc, mask, 64);
                if (ob < b || (ob == b && oc < cc)) { b = ob; cc = oc; }
            }
            if (cl == 0) {
                int row_l = w * 64 + m * 16 + kq * 4 + rr;
                bcLds[row_l] = cc;
                lsum += normLds[row_l] + b;   // ||x||^2 + ||e||^2 - 2 x.e
            }
        }
    lsum += __shfl_xor(lsum, 16, 64);
    lsum += __shfl_xor(lsum, 32, 64);
    if (lane == 0) atomicAdd(&lossSh, lsum);
    __syncthreads();                          // bcLds + lossSh ready

    // out[row] = E[bc[row]]  (== x + (q - x) to ~3e-7)
    #pragma unroll
    for (int i = 0; i < 64; ++i) {
        int g = i * 128 + tid;                // 8192 f4 = 128 rows x 64
        int rr = g >> 6, c4 = g & 63;
        int code = bcLds[rr];
        float4 q = *reinterpret_cast<const float4*>(E + (size_t)code * DIM + c4 * 4);
        *reinterpret_cast<float4*>(out + (size_t)(row0 + rr) * DIM + c4 * 4) = q;
    }
    if (tid == 0) atomicAdd(lossAcc, lossSh);
}

__global__ void vq_finalize(const float* __restrict__ lossAcc,
                            float* __restrict__ out) {
    out[(size_t)N_ROWS * DIM] = 1.25f * lossAcc[0] / (float)((size_t)N_ROWS * DIM);
}

extern "C" void kernel_launch(void* const* d_in, const int* in_sizes, int n_in,
                              void* d_out, int out_size, void* d_ws, size_t ws_size,
                              hipStream_t stream) {
    const float* X = (const float*)d_in[0];
    const float* E = (const float*)d_in[1];
    float* out = (float*)d_out;

    char* ws = (char*)d_ws;
    float* lossAcc = (float*)(ws + WS_LOSS_OFF);
    float* enorm = (float*)(ws + WS_ENORM_OFF);
    ushort* Ebf = (ushort*)(ws + WS_EBF_OFF);

    hipMemsetAsync(lossAcc, 0, 4, stream);
    vq_prep<<<256, 256, 0, stream>>>(E, Ebf, enorm);
    vq_main<<<N_ROWS / 128, 128, 0, stream>>>(X, Ebf, enorm, E, out, lossAcc);
    vq_finalize<<<1, 1, 0, stream>>>(lossAcc, out);
}

// Round 6
// 97.359 us; speedup vs baseline: 1.1118x; 1.0837x over previous
//
#include <hip/hip_runtime.h>
#include <stdint.h>

#define N_ROWS 65536
#define K_CODES 1024
#define DIM 256

typedef unsigned int uint;
typedef unsigned short ushort;

// d_ws layout:
//   [0, 4K)       loss accumulator (first 4B)
//   [4K, 8K)      enorm[1024] fp32
//   [8K, +512K)   Ebf: bf16 codebook, 512B per code
#define WS_LOSS_OFF  0
#define WS_ENORM_OFF 4096
#define WS_EBF_OFF   8192

typedef __attribute__((ext_vector_type(8))) short bf16x8;
typedef __attribute__((ext_vector_type(4))) float f32x4;

__device__ __forceinline__ ushort f2bf(float f) {
    uint u = __float_as_uint(f);
    return (ushort)((u + 0x7FFFu + ((u >> 16) & 1u)) >> 16);   // RNE
}
__device__ __forceinline__ void gload_lds16(const void* g, void* l) {
    __builtin_amdgcn_global_load_lds(
        (const __attribute__((address_space(1))) void*)g,
        (__attribute__((address_space(3))) void*)l, 16, 0, 0);
}

// ---- prep: E -> bf16 codebook + exact fp32 squared norms ------------------
__global__ __launch_bounds__(256) void vq_prep(const float* __restrict__ E,
                                               ushort* __restrict__ Ebf,
                                               float* __restrict__ enorm) {
    int id = blockIdx.x * 256 + threadIdx.x;      // 65536 = 1024 codes * 64 f4
    int code = id >> 6, c4 = id & 63;
    float4 v = *reinterpret_cast<const float4*>(E + (size_t)code * DIM + c4 * 4);
    uint2 hi;
    hi.x = (uint)f2bf(v.x) | ((uint)f2bf(v.y) << 16);
    hi.y = (uint)f2bf(v.z) | ((uint)f2bf(v.w) << 16);
    *reinterpret_cast<uint2*>((char*)Ebf + (size_t)code * 512 + c4 * 8) = hi;

    float s = v.x * v.x + v.y * v.y + v.z * v.z + v.w * v.w;
    #pragma unroll
    for (int m = 32; m >= 1; m >>= 1) s += __shfl_down(s, m, 64);
    if (c4 == 0) enorm[code] = s;
}

// ---- fused main ------------------------------------------------------------
// Block: 256 thr = 4 waves, 256 rows (wave w owns rows w*64..+63, m=4, A in regs).
// B: 64 tiles of 16 codes (8KB), 5-deep rotation, cooperative staging via
// global_load_lds. Per tile: issue stage(t+3) -> counted vmcnt(6) -> ONE
// s_barrier -> 32 MFMA. 5 buffers make stage(t+3) vs readers-of-(t-1) safe
// with a single barrier (slot gap 4 mod 5 != 0). Grid 256 -> 2 blocks/CU,
// 8 waves/CU for TLP. No vm-drain in the loop (T4).
__global__ __launch_bounds__(256, 2) void vq_main(const float* __restrict__ X,
                                                  const ushort* __restrict__ Ebf,
                                                  const float* __restrict__ enorm,
                                                  const float* __restrict__ E,
                                                  float* __restrict__ out,
                                                  float* __restrict__ lossAcc) {
    __shared__ __align__(16) unsigned char bsm[5 * 8192];   // 5 x 16-code tiles
    __shared__ float enormLds[1024];
    __shared__ float normLds[256];
    __shared__ int   bcLds[256];
    __shared__ float lossSh;

    const int tid = threadIdx.x;
    const int lane = tid & 63;
    const int w = tid >> 6;          // wave 0..3
    const int cl = lane & 15;
    const int kq = lane >> 4;
    const int row0 = blockIdx.x * 256;

    auto stageB = [&](int tile, int slot) {
        unsigned char* dst = bsm + slot * 8192;
        const unsigned char* src = (const unsigned char*)Ebf + (size_t)(tile * 16) * 512;
        #pragma unroll
        for (int j = 0; j < 2; ++j) {
            int o = j * 4096 + tid * 16;             // = uniform + lane*16 per wave
            int rr = o >> 9;                         // code row in tile (0..15)
            int cb = (o & 511) ^ ((rr & 7) << 4);    // pre-swizzled source (rule 21)
            gload_lds16(src + rr * 512 + cb, dst + o);
        }
    };

    // ---- A phase: global -> reg bf16 frags + exact fp32 row norms (vmem 1st)
    bf16x8 aF[4][8];
    #pragma unroll
    for (int m = 0; m < 4; ++m) {
        const float* rp = X + (size_t)(row0 + w * 64 + m * 16 + cl) * DIM;
        float s = 0.f;
        #pragma unroll
        for (int ks = 0; ks < 8; ++ks) {
            float4 v0 = *reinterpret_cast<const float4*>(rp + ks * 32 + kq * 8);
            float4 v1 = *reinterpret_cast<const float4*>(rp + ks * 32 + kq * 8 + 4);
            float e[8] = {v0.x, v0.y, v0.z, v0.w, v1.x, v1.y, v1.z, v1.w};
            bf16x8 f;
            #pragma unroll
            for (int j = 0; j < 8; ++j) {
                f[j] = (short)f2bf(e[j]);
                s = fmaf(e[j], e[j], s);
            }
            aF[m][ks] = f;
        }
        s += __shfl_xor(s, 16, 64);
        s += __shfl_xor(s, 32, 64);
        if (kq == 0) normLds[w * 64 + m * 16 + cl] = s;
    }

    // enorm -> LDS (1024 f32; one float4 per thread)
    reinterpret_cast<float4*>(enormLds)[tid] =
        reinterpret_cast<const float4*>(enorm)[tid];
    if (tid == 0) lossSh = 0.f;

    // prime the pipeline (newest vmem ops -> counted waits below are valid)
    stageB(0, 0);
    stageB(1, 1);
    stageB(2, 2);
    __syncthreads();     // one-time full drain: A/enorm/norm + stages 0-2 ready

    float best[4][4];
    int bcode[4][4];
    #pragma unroll
    for (int m = 0; m < 4; ++m)
        #pragma unroll
        for (int rr = 0; rr < 4; ++rr) { best[m][rr] = 3.4e38f; bcode[m][rr] = 0; }

    for (int t = 0; t < 64; ++t) {
        if (t <= 60) stageB(t + 3, (t + 3) % 5);      // issue-early (T14)
        // counted wait: my share of stage(t) landed; t+1..t+3 in flight (T4)
        if (t <= 60)      { asm volatile("s_waitcnt vmcnt(6)" ::: "memory"); }
        else if (t == 61) { asm volatile("s_waitcnt vmcnt(4)" ::: "memory"); }
        else if (t == 62) { asm volatile("s_waitcnt vmcnt(2)" ::: "memory"); }
        else              { asm volatile("s_waitcnt vmcnt(0)" ::: "memory"); }
        __builtin_amdgcn_s_barrier();                 // everyone's stage(t) visible
        __builtin_amdgcn_sched_barrier(0);

        const unsigned char* bb = bsm + (t % 5) * 8192;
        float en = enormLds[t * 16 + cl];

        f32x4 acc[4];
        #pragma unroll
        for (int m = 0; m < 4; ++m) {
            f32x4 z = {0.f, 0.f, 0.f, 0.f};
            acc[m] = z;
        }

        __builtin_amdgcn_s_setprio(1);
        #pragma unroll
        for (int ks = 0; ks < 8; ++ks) {
            bf16x8 bf = *reinterpret_cast<const bf16x8*>(
                bb + cl * 512 + ((ks * 64 + kq * 16) ^ ((cl & 7) << 4)));
            #pragma unroll
            for (int m = 0; m < 4; ++m)
                acc[m] = __builtin_amdgcn_mfma_f32_16x16x32_bf16(
                    aF[m][ks], bf, acc[m], 0, 0, 0);
        }
        __builtin_amdgcn_s_setprio(0);

        // fold (codes ascend across t -> strict < keeps first occurrence)
        int codeN = t * 16 + cl;
        #pragma unroll
        for (int m = 0; m < 4; ++m)
            #pragma unroll
            for (int rr = 0; rr < 4; ++rr) {
                float sc = fmaf(-2.f, acc[m][rr], en);
                if (sc < best[m][rr]) { best[m][rr] = sc; bcode[m][rr] = codeN; }
            }
    }

    // epilogue: cross-cl argmin reduce; C-row = m*16 + kq*4 + rr (m89 layout)
    float lsum = 0.f;
    #pragma unroll
    for (int m = 0; m < 4; ++m)
        #pragma unroll
        for (int rr = 0; rr < 4; ++rr) {
            float b = best[m][rr];
            int cc = bcode[m][rr];
            #pragma unroll
            for (int mask = 1; mask < 16; mask <<= 1) {
                float ob = __shfl_xor(b, mask, 64);
                int oc = __shfl_xor(cc, mask, 64);
                if (ob < b || (ob == b && oc < cc)) { b = ob; cc = oc; }
            }
            if (cl == 0) {
                int row_l = w * 64 + m * 16 + kq * 4 + rr;
                bcLds[row_l] = cc;
                lsum += normLds[row_l] + b;   // ||x||^2 + ||e||^2 - 2 x.e
            }
        }
    lsum += __shfl_xor(lsum, 16, 64);
    lsum += __shfl_xor(lsum, 32, 64);
    if (lane == 0) atomicAdd(&lossSh, lsum);
    __syncthreads();                          // bcLds + lossSh ready

    // out[row] = E[bc[row]]  (== x + (q - x) to ~3e-7)
    #pragma unroll 4
    for (int i = 0; i < 64; ++i) {
        int g = i * 256 + tid;                // 16384 f4 = 256 rows x 64
        int rr = g >> 6, c4 = g & 63;
        int code = bcLds[rr];
        float4 q = *reinterpret_cast<const float4*>(E + (size_t)code * DIM + c4 * 4);
        *reinterpret_cast<float4*>(out + (size_t)(row0 + rr) * DIM + c4 * 4) = q;
    }
    if (tid == 0) atomicAdd(lossAcc, lossSh);
}

__global__ void vq_finalize(const float* __restrict__ lossAcc,
                            float* __restrict__ out) {
    out[(size_t)N_ROWS * DIM] = 1.25f * lossAcc[0] / (float)((size_t)N_ROWS * DIM);
}

extern "C" void kernel_launch(void* const* d_in, const int* in_sizes, int n_in,
                              void* d_out, int out_size, void* d_ws, size_t ws_size,
                              hipStream_t stream) {
    const float* X = (const float*)d_in[0];
    const float* E = (const float*)d_in[1];
    float* out = (float*)d_out;

    char* ws = (char*)d_ws;
    float* lossAcc = (float*)(ws + WS_LOSS_OFF);
    float* enorm = (float*)(ws + WS_ENORM_OFF);
    ushort* Ebf = (ushort*)(ws + WS_EBF_OFF);

    hipMemsetAsync(lossAcc, 0, 4, stream);
    vq_prep<<<256, 256, 0, stream>>>(E, Ebf, enorm);
    vq_main<<<N_ROWS / 256, 256, 0, stream>>>(X, Ebf, enorm, E, out, lossAcc);
    vq_finalize<<<1, 1, 0, stream>>>(lossAcc, out);
}

// Round 7
// 81.846 us; speedup vs baseline: 1.3226x; 1.1895x over previous
//
#include <hip/hip_runtime.h>
#include <stdint.h>

#define N_ROWS 65536
#define K_CODES 1024
#define DIM 256

typedef unsigned int uint;
typedef unsigned short ushort;

// d_ws layout:
//   [0, 4K)       loss accumulator (first 4B)
//   [4K, 8K)      enorm[1024] fp32
//   [8K, +512K)   Ebf: bf16 codebook, 512B per code
#define WS_LOSS_OFF  0
#define WS_ENORM_OFF 4096
#define WS_EBF_OFF   8192

typedef __attribute__((ext_vector_type(8))) short bf16x8;
typedef __attribute__((ext_vector_type(4))) float f32x4;

__device__ __forceinline__ ushort f2bf(float f) {
    uint u = __float_as_uint(f);
    return (ushort)((u + 0x7FFFu + ((u >> 16) & 1u)) >> 16);   // RNE
}
__device__ __forceinline__ void gload_lds16(const void* g, void* l) {
    __builtin_amdgcn_global_load_lds(
        (const __attribute__((address_space(1))) void*)g,
        (__attribute__((address_space(3))) void*)l, 16, 0, 0);
}

// ---- prep: E -> bf16 codebook + exact fp32 squared norms ------------------
__global__ __launch_bounds__(256) void vq_prep(const float* __restrict__ E,
                                               ushort* __restrict__ Ebf,
                                               float* __restrict__ enorm) {
    int id = blockIdx.x * 256 + threadIdx.x;      // 65536 = 1024 codes * 64 f4
    int code = id >> 6, c4 = id & 63;
    float4 v = *reinterpret_cast<const float4*>(E + (size_t)code * DIM + c4 * 4);
    uint2 hi;
    hi.x = (uint)f2bf(v.x) | ((uint)f2bf(v.y) << 16);
    hi.y = (uint)f2bf(v.z) | ((uint)f2bf(v.w) << 16);
    *reinterpret_cast<uint2*>((char*)Ebf + (size_t)code * 512 + c4 * 8) = hi;

    float s = v.x * v.x + v.y * v.y + v.z * v.z + v.w * v.w;
    #pragma unroll
    for (int m = 32; m >= 1; m >>= 1) s += __shfl_down(s, m, 64);
    if (c4 == 0) enorm[code] = s;
}

// ---- fused main ------------------------------------------------------------
// Block: 256 thr = 4 waves, 128 rows (wave w owns rows w*32..+31, m=2 -> aF
// is 64 VGPR, NO SPILL). B: 64 tiles of 16 codes (8KB), 5-deep rotation,
// cooperative global_load_lds staging. Per tile: issue stage(t+3) ->
// counted vmcnt(6) -> ONE s_barrier -> 16 MFMA. Grid 512 -> 2 blocks/CU,
// 8 waves/CU (2/SIMD) for TLP. No vm-drain in the loop (T4).
__global__ __launch_bounds__(256, 2) void vq_main(const float* __restrict__ X,
                                                  const ushort* __restrict__ Ebf,
                                                  const float* __restrict__ enorm,
                                                  const float* __restrict__ E,
                                                  float* __restrict__ out,
                                                  float* __restrict__ lossAcc) {
    __shared__ __align__(16) unsigned char bsm[5 * 8192];   // 5 x 16-code tiles
    __shared__ float enormLds[1024];
    __shared__ float normLds[128];
    __shared__ int   bcLds[128];
    __shared__ float lossSh;

    const int tid = threadIdx.x;
    const int lane = tid & 63;
    const int w = tid >> 6;          // wave 0..3
    const int cl = lane & 15;
    const int kq = lane >> 4;
    const int row0 = blockIdx.x * 128;

    auto stageB = [&](int tile, int slot) {
        unsigned char* dst = bsm + slot * 8192;
        const unsigned char* src = (const unsigned char*)Ebf + (size_t)(tile * 16) * 512;
        #pragma unroll
        for (int j = 0; j < 2; ++j) {
            int o = j * 4096 + tid * 16;             // wave-uniform base + lane*16
            int rr = o >> 9;                         // code row in tile (0..15)
            int cb = (o & 511) ^ ((rr & 7) << 4);    // pre-swizzled source (rule 21)
            gload_lds16(src + rr * 512 + cb, dst + o);
        }
    };

    // ---- A phase: global -> reg bf16 frags (m=2) + exact fp32 row norms ----
    bf16x8 aF[2][8];
    #pragma unroll
    for (int m = 0; m < 2; ++m) {
        const float* rp = X + (size_t)(row0 + w * 32 + m * 16 + cl) * DIM;
        float s = 0.f;
        #pragma unroll
        for (int ks = 0; ks < 8; ++ks) {
            float4 v0 = *reinterpret_cast<const float4*>(rp + ks * 32 + kq * 8);
            float4 v1 = *reinterpret_cast<const float4*>(rp + ks * 32 + kq * 8 + 4);
            float e[8] = {v0.x, v0.y, v0.z, v0.w, v1.x, v1.y, v1.z, v1.w};
            bf16x8 f;
            #pragma unroll
            for (int j = 0; j < 8; ++j) {
                f[j] = (short)f2bf(e[j]);
                s = fmaf(e[j], e[j], s);
            }
            aF[m][ks] = f;
        }
        s += __shfl_xor(s, 16, 64);
        s += __shfl_xor(s, 32, 64);
        if (kq == 0) normLds[w * 32 + m * 16 + cl] = s;
    }

    // enorm -> LDS (1024 f32; one float4 per thread)
    reinterpret_cast<float4*>(enormLds)[tid] =
        reinterpret_cast<const float4*>(enorm)[tid];
    if (tid == 0) lossSh = 0.f;

    // prime the pipeline
    stageB(0, 0);
    stageB(1, 1);
    stageB(2, 2);
    __syncthreads();     // one-time full drain: A/enorm/norm + stages 0-2 ready

    float best[2][4];
    int bcode[2][4];
    #pragma unroll
    for (int m = 0; m < 2; ++m)
        #pragma unroll
        for (int rr = 0; rr < 4; ++rr) { best[m][rr] = 3.4e38f; bcode[m][rr] = 0; }

    for (int t = 0; t < 64; ++t) {
        if (t <= 60) stageB(t + 3, (t + 3) % 5);      // issue-early (T14)
        // counted wait: my share of stage(t) landed; t+1..t+3 in flight (T4)
        if (t <= 60)      { asm volatile("s_waitcnt vmcnt(6)" ::: "memory"); }
        else if (t == 61) { asm volatile("s_waitcnt vmcnt(4)" ::: "memory"); }
        else if (t == 62) { asm volatile("s_waitcnt vmcnt(2)" ::: "memory"); }
        else              { asm volatile("s_waitcnt vmcnt(0)" ::: "memory"); }
        __builtin_amdgcn_s_barrier();                 // everyone's stage(t) visible
        __builtin_amdgcn_sched_barrier(0);

        const unsigned char* bb = bsm + (t % 5) * 8192;
        float en = enormLds[t * 16 + cl];

        f32x4 acc[2];
        #pragma unroll
        for (int m = 0; m < 2; ++m) {
            f32x4 z = {0.f, 0.f, 0.f, 0.f};
            acc[m] = z;
        }

        __builtin_amdgcn_s_setprio(1);
        #pragma unroll
        for (int ks = 0; ks < 8; ++ks) {
            bf16x8 bf = *reinterpret_cast<const bf16x8*>(
                bb + cl * 512 + ((ks * 64 + kq * 16) ^ ((cl & 7) << 4)));
            #pragma unroll
            for (int m = 0; m < 2; ++m)
                acc[m] = __builtin_amdgcn_mfma_f32_16x16x32_bf16(
                    aF[m][ks], bf, acc[m], 0, 0, 0);
        }
        __builtin_amdgcn_s_setprio(0);

        // fold (codes ascend across t -> strict < keeps first occurrence)
        int codeN = t * 16 + cl;
        #pragma unroll
        for (int m = 0; m < 2; ++m)
            #pragma unroll
            for (int rr = 0; rr < 4; ++rr) {
                float sc = fmaf(-2.f, acc[m][rr], en);
                if (sc < best[m][rr]) { best[m][rr] = sc; bcode[m][rr] = codeN; }
            }
    }

    // epilogue: cross-cl argmin reduce; C-row = m*16 + kq*4 + rr (m89 layout)
    float lsum = 0.f;
    #pragma unroll
    for (int m = 0; m < 2; ++m)
        #pragma unroll
        for (int rr = 0; rr < 4; ++rr) {
            float b = best[m][rr];
            int cc = bcode[m][rr];
            #pragma unroll
            for (int mask = 1; mask < 16; mask <<= 1) {
                float ob = __shfl_xor(b, mask, 64);
                int oc = __shfl_xor(cc, mask, 64);
                if (ob < b || (ob == b && oc < cc)) { b = ob; cc = oc; }
            }
            if (cl == 0) {
                int row_l = w * 32 + m * 16 + kq * 4 + rr;
                bcLds[row_l] = cc;
                lsum += normLds[row_l] + b;   // ||x||^2 + ||e||^2 - 2 x.e
            }
        }
    lsum += __shfl_xor(lsum, 16, 64);
    lsum += __shfl_xor(lsum, 32, 64);
    if (lane == 0) atomicAdd(&lossSh, lsum);
    __syncthreads();                          // bcLds + lossSh ready

    // out[row] = E[bc[row]]  (== x + (q - x) to ~3e-7)
    #pragma unroll 4
    for (int i = 0; i < 32; ++i) {
        int g = i * 256 + tid;                // 8192 f4 = 128 rows x 64
        int rr = g >> 6, c4 = g & 63;
        int code = bcLds[rr];
        float4 q = *reinterpret_cast<const float4*>(E + (size_t)code * DIM + c4 * 4);
        *reinterpret_cast<float4*>(out + (size_t)(row0 + rr) * DIM + c4 * 4) = q;
    }
    if (tid == 0) atomicAdd(lossAcc, lossSh);
}

__global__ void vq_finalize(const float* __restrict__ lossAcc,
                            float* __restrict__ out) {
    out[(size_t)N_ROWS * DIM] = 1.25f * lossAcc[0] / (float)((size_t)N_ROWS * DIM);
}

extern "C" void kernel_launch(void* const* d_in, const int* in_sizes, int n_in,
                              void* d_out, int out_size, void* d_ws, size_t ws_size,
                              hipStream_t stream) {
    const float* X = (const float*)d_in[0];
    const float* E = (const float*)d_in[1];
    float* out = (float*)d_out;

    char* ws = (char*)d_ws;
    float* lossAcc = (float*)(ws + WS_LOSS_OFF);
    float* enorm = (float*)(ws + WS_ENORM_OFF);
    ushort* Ebf = (ushort*)(ws + WS_EBF_OFF);

    hipMemsetAsync(lossAcc, 0, 4, stream);
    vq_prep<<<256, 256, 0, stream>>>(E, Ebf, enorm);
    vq_main<<<N_ROWS / 128, 256, 0, stream>>>(X, Ebf, enorm, E, out, lossAcc);
    vq_finalize<<<1, 1, 0, stream>>>(lossAcc, out);
}